// Round 8
// baseline (150.960 us; speedup 1.0000x reference)
//
#include <hip/hip_runtime.h>

#define N 1024
#define E 256
#define H 128
#define NBLK 528
#define QSTR 136  // halves; 272 B row stride -> conflict-free b128

typedef _Float16 hv2 __attribute__((ext_vector_type(2)));
typedef _Float16 half_t;

__device__ __forceinline__ float dot2_acc(hv2 a, hv2 b, float c) {
#if __has_builtin(__builtin_amdgcn_fdot2)
    return __builtin_amdgcn_fdot2(a, b, c, false);
#else
    return c + (float)a.x * (float)b.x + (float)a.y * (float)b.y;
#endif
}

__device__ __forceinline__ hv2 relu_add2(hv2 a, hv2 b) {
    hv2 s = a + b;
    hv2 z = (hv2)(_Float16)0.f;
    return __builtin_elementwise_max(s, z);
}

// FULL grid barrier, spread arrivals (fixes round-4's 45us single-line RMW
// convoy: 528 x ~200cy serialized). 32 counter lines (128B apart, <=17 RMWs
// each, parallel across lines) + block-0 aggregator + one release flag.
// Fence protocol identical to the round-4 verified barrier:
// producer fence-release -> atomic arrive; aggregator reads -> full fence ->
// release flag; consumer sees flag -> fence-acquire. No partial sync (the
// round-6 scheme) anywhere.
__device__ __forceinline__ void full_barrier(int* bar) {
    __syncthreads();  // drains each wave's stores (vmcnt) before arrival
    if (threadIdx.x == 0) {
        __threadfence();  // release: this block's writes device-visible
        atomicAdd(&bar[(blockIdx.x & 31) * 32], 1);
        if (blockIdx.x == 0) {
            int total;
            do {
                total = 0;
#pragma unroll
                for (int i = 0; i < 32; ++i)
                    total += __hip_atomic_load(&bar[i * 32], __ATOMIC_RELAXED,
                                               __HIP_MEMORY_SCOPE_AGENT);
            } while (total < NBLK);
            __threadfence();  // order counter reads before flag store
            __hip_atomic_store(&bar[32 * 32], 1, __ATOMIC_RELEASE,
                               __HIP_MEMORY_SCOPE_AGENT);
        }
        while (__hip_atomic_load(&bar[32 * 32], __ATOMIC_RELAXED,
                                 __HIP_MEMORY_SCOPE_AGENT) == 0) {}
        __threadfence();  // acquire: invalidate stale lines before phase B reads
    }
    __syncthreads();
}

// One launch, two phases separated by the full barrier:
//  phase A (blocks 0..511): round-5-EXACT 2-row unfolded proj (verified fast:
//    512 blocks -> 2 waves/SIMD; round-7 showed 4-row/256-block is latency-
//    crippled at 1 wave/SIMD despite half the L2 traffic).
//  phase B (all 528 blocks): round-5-EXACT 32x32 upper-tri pair tile.
__global__ __launch_bounds__(256, 3) void fused_kernel(
    const float* __restrict__ x, const float* __restrict__ P,
    const float* __restrict__ Wq, const float* __restrict__ bq,
    const float* __restrict__ Wk, const float* __restrict__ bk,
    const float* __restrict__ Wc, const float* __restrict__ bc,
    const float* __restrict__ W1, const float* __restrict__ b1,
    const float* __restrict__ W2, const float* __restrict__ b2,
    int* bar,
    half_t* __restrict__ qh, half_t* __restrict__ kh,
    float* __restrict__ out) {
    __shared__ __align__(16) half_t qs[32][QSTR];
    __shared__ __align__(16) half_t ks[32][QSTR];
    __shared__ __align__(16) half_t w2s[H];
    // proj scratch aliased entirely inside qs (1792 floats = 7168 B < 8704 B):
    float* fs  = (float*)&qs[0][0];
    float* xs  = fs;          // 256
    float* p_s = fs + 256;    // 512 (2 rows)
    float* pc  = fs + 768;    // 256
    float* aq  = fs + 1024;   // 128
    float* ak  = fs + 1152;   // 128
    float* sv  = fs + 1280;   // 2*256

    int b = blockIdx.x, t = threadIdx.x;
    int h = t & (H - 1);
    int c = t >> 7;  // 0 = q-side, 1 = k-side

    // ---------------- phase A: proj, 2 rows (blocks 0..511) ----------------
    if (b < N / 2) {
        int i0 = b * 2;
        if (t < 64) ((float4*)xs)[t] = ((const float4*)x)[t];
        else if (t < 192) ((float4*)p_s)[t - 64] = ((const float4*)(P + i0 * E))[t - 64];
        __syncthreads();

        // ctx partials: side c covers e in [c*128, c*128+128)
        {
            float p = 0.f;
#pragma unroll 8
            for (int e = c * H; e < c * H + H; ++e) p += xs[e] * Wc[e * H + h];
            pc[c * H + h] = p;
        }
        __syncthreads();
        if (t < H) {
            float ctxv = fmaxf(pc[t] + pc[H + t] + bc[t], 0.f);
            aq[t] = bq[t] + ctxv;
            ak[t] = bk[t] + ctxv;
        }
        __syncthreads();

        // s_i = P_i @ W + (b + ctx); both rows share each W column load
        {
            const float* W = c ? Wk : Wq;
            float a0 = c ? ak[h] : aq[h];
            float a1 = a0;
            for (int e = 0; e < E; e += 8) {
                float m0 = W[(e + 0) * H + h];
                float m1 = W[(e + 1) * H + h];
                float m2 = W[(e + 2) * H + h];
                float m3 = W[(e + 3) * H + h];
                float m4 = W[(e + 4) * H + h];
                float m5 = W[(e + 5) * H + h];
                float m6 = W[(e + 6) * H + h];
                float m7 = W[(e + 7) * H + h];
                float4 p0a = *(const float4*)&p_s[0 * E + e];
                float4 p0b = *(const float4*)&p_s[0 * E + e + 4];
                float4 p1a = *(const float4*)&p_s[1 * E + e];
                float4 p1b = *(const float4*)&p_s[1 * E + e + 4];
                a0 += p0a.x * m0 + p0a.y * m1 + p0a.z * m2 + p0a.w * m3
                    + p0b.x * m4 + p0b.y * m5 + p0b.z * m6 + p0b.w * m7;
                a1 += p1a.x * m0 + p1a.y * m1 + p1a.z * m2 + p1a.w * m3
                    + p1b.x * m4 + p1b.y * m5 + p1b.z * m6 + p1b.w * m7;
            }
            sv[0 * 2 * H + c * H + h] = a0;
            sv[1 * 2 * H + c * H + h] = a1;
        }
        __syncthreads();

        // qp_i = s_i @ W1a + b1 / kp_i = s_i @ W1b; sv reads wave-broadcast
        {
            const float* W1c = W1 + c * H * H;
            const float* S0 = sv + 0 * 2 * H + c * H;
            const float* S1 = sv + 1 * 2 * H + c * H;
            float a0 = c ? 0.f : b1[h];
            float a1 = a0;
            for (int r = 0; r < H; r += 8) {
                float w0 = W1c[(r + 0) * H + h];
                float w1 = W1c[(r + 1) * H + h];
                float w2 = W1c[(r + 2) * H + h];
                float w3 = W1c[(r + 3) * H + h];
                float w4 = W1c[(r + 4) * H + h];
                float w5 = W1c[(r + 5) * H + h];
                float w6 = W1c[(r + 6) * H + h];
                float w7 = W1c[(r + 7) * H + h];
                a0 += S0[r + 0] * w0 + S0[r + 1] * w1 + S0[r + 2] * w2 + S0[r + 3] * w3
                    + S0[r + 4] * w4 + S0[r + 5] * w5 + S0[r + 6] * w6 + S0[r + 7] * w7;
                a1 += S1[r + 0] * w0 + S1[r + 1] * w1 + S1[r + 2] * w2 + S1[r + 3] * w3
                    + S1[r + 4] * w4 + S1[r + 5] * w5 + S1[r + 6] * w6 + S1[r + 7] * w7;
            }
            half_t* O = c ? kh : qh;
            O[(i0 + 0) * H + h] = (half_t)a0;
            O[(i0 + 1) * H + h] = (half_t)a1;
        }
    }

    full_barrier(bar);

    // ---------------- phase B: pair tile (all 528 blocks) ----------------
    {
        int tid = b;
        int bi = (int)((65.0f - sqrtf(4225.0f - 8.0f * (float)tid)) * 0.5f);
        while (bi > 0 && tid < 32 * bi - bi * (bi - 1) / 2) --bi;
        while (tid >= 32 * (bi + 1) - (bi + 1) * bi / 2) ++bi;
        int bj = bi + (tid - (32 * bi - bi * (bi - 1) / 2));

        if (t < H) w2s[t] = (half_t)W2[t];
        float b2v = b2[0];

        const float4* qh4 = (const float4*)(qh + bi * 32 * H);
        const float4* kh4 = (const float4*)(kh + bj * 32 * H);
#pragma unroll
        for (int v = 0; v < 2; ++v) {
            int idx = v * 256 + t;  // 0..511 : 32 rows x 16 float4
            int r = idx >> 4, cc = idx & 15;
            float4 q = qh4[idx];
            float4 k = kh4[idx];
            *(float4*)&qs[r][cc * 8] = q;
            *(float4*)&ks[r][cc * 8] = k;
        }
        __syncthreads();

        int jj  = t & 31;  // k row within tile
        int ti0 = t >> 5;  // q rows ti0, ti0+8, ti0+16, ti0+24
        float acc[4];
#pragma unroll
        for (int u = 0; u < 4; ++u) acc[u] = b2v;

        for (int h8 = 0; h8 < 16; ++h8) {
            float4 wf = *(const float4*)&w2s[h8 * 8];
            float4 kv = *(const float4*)&ks[jj][h8 * 8];
            const hv2* wp = (const hv2*)&wf;
            const hv2* kp2 = (const hv2*)&kv;
#pragma unroll
            for (int u = 0; u < 4; ++u) {
                float4 qf = *(const float4*)&qs[ti0 + u * 8][h8 * 8];
                const hv2* qp2 = (const hv2*)&qf;
#pragma unroll
                for (int s = 0; s < 4; ++s) {
                    hv2 sa = relu_add2(qp2[s], kp2[s]);
                    acc[u] = dot2_acc(sa, wp[s], acc[u]);
                }
            }
        }

#pragma unroll
        for (int u = 0; u < 4; ++u) {
            int i = bi * 32 + ti0 + u * 8;
            int j = bj * 32 + jj;
            if (j > i) {
                int base = i * (2 * N - i - 1) / 2;
                out[base + (j - i - 1)] = acc[u];
            }
        }
    }
}

extern "C" void kernel_launch(void* const* d_in, const int* in_sizes, int n_in,
                              void* d_out, int out_size, void* d_ws, size_t ws_size,
                              hipStream_t stream) {
    const float* x  = (const float*)d_in[0];
    const float* P  = (const float*)d_in[1];
    const float* Wq = (const float*)d_in[2];
    const float* bq = (const float*)d_in[3];
    const float* Wk = (const float*)d_in[4];
    const float* bk = (const float*)d_in[5];
    const float* Wc = (const float*)d_in[6];
    const float* bc = (const float*)d_in[7];
    const float* W1 = (const float*)d_in[8];
    const float* b1 = (const float*)d_in[9];
    const float* W2 = (const float*)d_in[10];
    const float* b2 = (const float*)d_in[11];
    float* out = (float*)d_out;

    int* bar   = (int*)d_ws;                     // 32 counter lines + flag, 8 KB
    half_t* qh = (half_t*)((char*)d_ws + 8192);  // 1024*128 halves
    half_t* kh = qh + N * H;                     // 1024*128 halves

    hipMemsetAsync(d_ws, 0, 8192, stream);  // zero barrier state (ws is poisoned)

    void* args[] = {
        (void*)&x,  (void*)&P,  (void*)&Wq, (void*)&bq, (void*)&Wk, (void*)&bk,
        (void*)&Wc, (void*)&bc, (void*)&W1, (void*)&b1, (void*)&W2, (void*)&b2,
        (void*)&bar, (void*)&qh, (void*)&kh, (void*)&out};
    hipLaunchCooperativeKernel((const void*)fused_kernel, dim3(NBLK), dim3(256),
                               args, 0, stream);
}

// Round 9
// 103.128 us; speedup vs baseline: 1.4638x; 1.4638x over previous
//
#include <hip/hip_runtime.h>

#define N 1024
#define E 256
#define H 128

typedef _Float16 hv2 __attribute__((ext_vector_type(2)));
typedef _Float16 half_t;

__device__ __forceinline__ float dot2_acc(hv2 a, hv2 b, float c) {
#if __has_builtin(__builtin_amdgcn_fdot2)
    return __builtin_amdgcn_fdot2(a, b, c, false);
#else
    return c + (float)a.x * (float)b.x + (float)a.y * (float)b.y;
#endif
}

__device__ __forceinline__ hv2 relu_add2(hv2 a, hv2 b) {
    hv2 s = a + b;
    hv2 z = (hv2)(_Float16)0.f;
    return __builtin_elementwise_max(s, z);
}

// proj: 256 blocks x 512 threads. Each block = TWO virtual round-5 blocks:
// thread group g = tid>>8 runs the verified 2-row proj body verbatim on its
// own LDS slice (rows blockIdx.x*4 + g*2 .. +1). Same occupancy as round 5
// (8 waves/CU = 2/SIMD -- round 7 proved 1 wave/SIMD is latency-crippled),
// but both halves issue identical weight-column addresses in near-lockstep,
// so L1 dedups them -> per-block weight traffic serves 4 rows instead of 2
// (262 MB -> ~131 MB L2 traffic).
__global__ __launch_bounds__(512) void proj_kernel(
    const float* __restrict__ x, const float* __restrict__ P,
    const float* __restrict__ Wq, const float* __restrict__ bq,
    const float* __restrict__ Wk, const float* __restrict__ bk,
    const float* __restrict__ Wc, const float* __restrict__ bc,
    const float* __restrict__ W1, const float* __restrict__ b1,
    half_t* __restrict__ qh, half_t* __restrict__ kh) {
    __shared__ __align__(16) float xs[E];          // shared by both halves
    __shared__ __align__(16) float p_s[2][2 * E];  // per-half: 2 P rows
    __shared__ float pc[2][2 * H];                 // per-half ctx partials
    __shared__ float aq[2][H], ak[2][H];           // per-half bq+ctx, bk+ctx
    __shared__ float sv[2][2][2 * H];              // per-half s vectors

    int tid = threadIdx.x;
    int g = tid >> 8;        // virtual block 0/1
    int t = tid & 255;       // thread within virtual block
    int vb = blockIdx.x * 2 + g;  // virtual block id 0..511
    int i0 = vb * 2;

    if (tid < 64) ((float4*)xs)[tid] = ((const float4*)x)[tid];
    if (t >= 64 && t < 192)
        ((float4*)p_s[g])[t - 64] = ((const float4*)(P + i0 * E))[t - 64];
    __syncthreads();

    int h = t & (H - 1);
    int c = t >> 7;  // 0 = q-side, 1 = k-side

    // ctx partials: side c covers e in [c*128, c*128+128)
    {
        float p = 0.f;
#pragma unroll 8
        for (int e = c * H; e < c * H + H; ++e) p += xs[e] * Wc[e * H + h];
        pc[g][c * H + h] = p;
    }
    __syncthreads();
    if (t < H) {
        float ctxv = fmaxf(pc[g][t] + pc[g][H + t] + bc[t], 0.f);
        aq[g][t] = bq[t] + ctxv;
        ak[g][t] = bk[t] + ctxv;
    }
    __syncthreads();

    // s_i = P_i @ W + (b + ctx); both rows share each W column load
    {
        const float* W = c ? Wk : Wq;
        float a0 = c ? ak[g][h] : aq[g][h];
        float a1 = a0;
        for (int e = 0; e < E; e += 8) {
            float m0 = W[(e + 0) * H + h];
            float m1 = W[(e + 1) * H + h];
            float m2 = W[(e + 2) * H + h];
            float m3 = W[(e + 3) * H + h];
            float m4 = W[(e + 4) * H + h];
            float m5 = W[(e + 5) * H + h];
            float m6 = W[(e + 6) * H + h];
            float m7 = W[(e + 7) * H + h];
            float4 p0a = *(const float4*)&p_s[g][0 * E + e];
            float4 p0b = *(const float4*)&p_s[g][0 * E + e + 4];
            float4 p1a = *(const float4*)&p_s[g][1 * E + e];
            float4 p1b = *(const float4*)&p_s[g][1 * E + e + 4];
            a0 += p0a.x * m0 + p0a.y * m1 + p0a.z * m2 + p0a.w * m3
                + p0b.x * m4 + p0b.y * m5 + p0b.z * m6 + p0b.w * m7;
            a1 += p1a.x * m0 + p1a.y * m1 + p1a.z * m2 + p1a.w * m3
                + p1b.x * m4 + p1b.y * m5 + p1b.z * m6 + p1b.w * m7;
        }
        sv[g][0][c * H + h] = a0;
        sv[g][1][c * H + h] = a1;
    }
    __syncthreads();

    // qp_i = s_i @ W1a + b1 (q-side) ; kp_i = s_i @ W1b (k-side).
    // sv reads are wave-broadcast (same addr across lanes).
    {
        const float* W1c = W1 + c * H * H;
        const float* S0 = &sv[g][0][c * H];
        const float* S1 = &sv[g][1][c * H];
        float a0 = c ? 0.f : b1[h];
        float a1 = a0;
        for (int r = 0; r < H; r += 8) {
            float w0 = W1c[(r + 0) * H + h];
            float w1 = W1c[(r + 1) * H + h];
            float w2 = W1c[(r + 2) * H + h];
            float w3 = W1c[(r + 3) * H + h];
            float w4 = W1c[(r + 4) * H + h];
            float w5 = W1c[(r + 5) * H + h];
            float w6 = W1c[(r + 6) * H + h];
            float w7 = W1c[(r + 7) * H + h];
            a0 += S0[r + 0] * w0 + S0[r + 1] * w1 + S0[r + 2] * w2 + S0[r + 3] * w3
                + S0[r + 4] * w4 + S0[r + 5] * w5 + S0[r + 6] * w6 + S0[r + 7] * w7;
            a1 += S1[r + 0] * w0 + S1[r + 1] * w1 + S1[r + 2] * w2 + S1[r + 3] * w3
                + S1[r + 4] * w4 + S1[r + 5] * w5 + S1[r + 6] * w6 + S1[r + 7] * w7;
        }
        half_t* O = c ? kh : qh;
        O[(i0 + 0) * H + h] = (half_t)a0;
        O[(i0 + 1) * H + h] = (half_t)a1;
    }
}

// pair: exact triangular tiling. 528 blocks, one 32x32 (bi<=bj) tile each.
// Per thread: 4 (i,j) pairs; f16 LDS + fdot2. (Unchanged, harness-verified.)
#define QSTR 136  // halves; 272 B row stride -> conflict-free b128
__global__ __launch_bounds__(256) void pair_kernel(
    const half_t* __restrict__ qh, const half_t* __restrict__ kh,
    const float* __restrict__ W2, const float* __restrict__ b2,
    float* __restrict__ out) {
    int tid = blockIdx.x;
    int bi = (int)((65.0f - sqrtf(4225.0f - 8.0f * (float)tid)) * 0.5f);
    while (bi > 0 && tid < 32 * bi - bi * (bi - 1) / 2) --bi;
    while (tid >= 32 * (bi + 1) - (bi + 1) * bi / 2) ++bi;
    int bj = bi + (tid - (32 * bi - bi * (bi - 1) / 2));

    __shared__ __align__(16) half_t qs[32][QSTR];
    __shared__ __align__(16) half_t ks[32][QSTR];
    __shared__ __align__(16) half_t w2s[H];

    int t = threadIdx.x;
    if (t < H) w2s[t] = (half_t)W2[t];

    const float4* qh4 = (const float4*)(qh + bi * 32 * H);
    const float4* kh4 = (const float4*)(kh + bj * 32 * H);
#pragma unroll
    for (int v = 0; v < 2; ++v) {
        int idx = v * 256 + t;  // 0..511 : 32 rows x 16 float4
        int r = idx >> 4, c = idx & 15;
        float4 q = qh4[idx];
        float4 k = kh4[idx];
        *(float4*)&qs[r][c * 8] = q;
        *(float4*)&ks[r][c * 8] = k;
    }
    __syncthreads();

    int jj  = t & 31;  // k row within tile
    int ti0 = t >> 5;  // q rows ti0, ti0+8, ti0+16, ti0+24
    float b2v = b2[0];
    float acc[4];
#pragma unroll
    for (int u = 0; u < 4; ++u) acc[u] = b2v;

    for (int h8 = 0; h8 < 16; ++h8) {
        float4 wf = *(const float4*)&w2s[h8 * 8];
        float4 kv = *(const float4*)&ks[jj][h8 * 8];
        const hv2* wp = (const hv2*)&wf;
        const hv2* kp2 = (const hv2*)&kv;
#pragma unroll
        for (int u = 0; u < 4; ++u) {
            float4 qf = *(const float4*)&qs[ti0 + u * 8][h8 * 8];
            const hv2* qp2 = (const hv2*)&qf;
#pragma unroll
            for (int s = 0; s < 4; ++s) {
                hv2 sa = relu_add2(qp2[s], kp2[s]);
                acc[u] = dot2_acc(sa, wp[s], acc[u]);
            }
        }
    }

#pragma unroll
    for (int u = 0; u < 4; ++u) {
        int i = bi * 32 + ti0 + u * 8;
        int j = bj * 32 + jj;
        if (j > i) {
            int base = i * (2 * N - i - 1) / 2;
            out[base + (j - i - 1)] = acc[u];
        }
    }
}

extern "C" void kernel_launch(void* const* d_in, const int* in_sizes, int n_in,
                              void* d_out, int out_size, void* d_ws, size_t ws_size,
                              hipStream_t stream) {
    const float* x  = (const float*)d_in[0];
    const float* P  = (const float*)d_in[1];
    const float* Wq = (const float*)d_in[2];
    const float* bq = (const float*)d_in[3];
    const float* Wk = (const float*)d_in[4];
    const float* bk = (const float*)d_in[5];
    const float* Wc = (const float*)d_in[6];
    const float* bc = (const float*)d_in[7];
    const float* W1 = (const float*)d_in[8];
    const float* b1 = (const float*)d_in[9];
    const float* W2 = (const float*)d_in[10];
    const float* b2 = (const float*)d_in[11];
    float* out = (float*)d_out;

    half_t* qh = (half_t*)d_ws;        // 1024*128 halves
    half_t* kh = qh + N * H;           // 1024*128 halves

    proj_kernel<<<N / 4, 512, 0, stream>>>(x, P, Wq, bq, Wk, bk, Wc, bc, W1, b1,
                                           qh, kh);
    pair_kernel<<<528, 256, 0, stream>>>(qh, kh, W2, b2, out);
}

// Round 10
// 96.352 us; speedup vs baseline: 1.5668x; 1.0703x over previous
//
#include <hip/hip_runtime.h>

#define N 1024
#define E 256
#define H 128

typedef _Float16 hv2 __attribute__((ext_vector_type(2)));
typedef _Float16 half_t;

__device__ __forceinline__ float dot2_acc(hv2 a, hv2 b, float c) {
#if __has_builtin(__builtin_amdgcn_fdot2)
    return __builtin_amdgcn_fdot2(a, b, c, false);
#else
    return c + (float)a.x * (float)b.x + (float)a.y * (float)b.y;
#endif
}

__device__ __forceinline__ hv2 relu_add2(hv2 a, hv2 b) {
    hv2 s = a + b;
    hv2 z = (hv2)(_Float16)0.f;
    return __builtin_elementwise_max(s, z);
}

// proj v3: side-split + e-split. 512 blocks x 256 threads (2 waves/SIMD, the
// occupancy R7 proved necessary). Block b: side = b&1 (q or k), rows
// i0=(b>>1)*4 .. +3. Thread t: h = t&127, g = t>>7 = e-half (or r-half).
// Each thread accumulates 4 rows in REGISTERS while walking half the weight
// range -> per-thread global loads 320 vs R5's ~515 (0.62x), weight traffic
// 262->164 MB. Reuse is in-thread, not cache-timing (R9's failed bet).
// Halves combined via LDS partials. Pure f32 refactor of verified R5 math.
__global__ __launch_bounds__(256) void proj_kernel(
    const float* __restrict__ x, const float* __restrict__ P,
    const float* __restrict__ Wq, const float* __restrict__ bq,
    const float* __restrict__ Wk, const float* __restrict__ bk,
    const float* __restrict__ Wc, const float* __restrict__ bc,
    const float* __restrict__ W1, const float* __restrict__ b1,
    half_t* __restrict__ qh, half_t* __restrict__ kh) {
    __shared__ __align__(16) float xs[E];       // next-state embedding
    __shared__ __align__(16) float p_s[4 * E];  // 4 P rows
    __shared__ float pc[2][H];                  // ctx partials by e-half
    __shared__ float av[H];                     // b_side + ctx
    __shared__ float sp[2][4][H];               // s partials by e-half
    __shared__ float sv[4][H];                  // s combined
    __shared__ float qpp[2][4][H];              // W1 partials by r-half

    int b = blockIdx.x, t = threadIdx.x;
    int side = b & 1;                // 0 = q, 1 = k
    int i0 = (b >> 1) * 4;           // first of 4 rows
    int h = t & (H - 1);
    int g = t >> 7;                  // e-half / r-half group

    if (t < 64) ((float4*)xs)[t] = ((const float4*)x)[t];
    ((float4*)p_s)[t] = ((const float4*)(P + i0 * E))[t];  // 256 f4 = 4 rows
    __syncthreads();

    // ctx partial over e-half g: pc[g][h] = sum_e xs[g*128+e] * Wc[g*128+e][h]
    {
        const float* Wce = Wc + g * H * H;
        const float* xg = xs + g * H;
        float p = 0.f;
#pragma unroll 8
        for (int e = 0; e < H; ++e) p += xg[e] * Wce[e * H + h];
        pc[g][h] = p;
    }
    __syncthreads();
    if (t < H) {
        float ctxv = fmaxf(pc[0][t] + pc[1][t] + bc[t], 0.f);
        av[t] = (side ? bk[t] : bq[t]) + ctxv;
    }
    __syncthreads();

    // s partials: 4 rows, e-half g.  s[r][h] = sum_e P[r][e]*W[e][h] (+av later)
    {
        const float* W = (side ? Wk : Wq) + g * H * H;
        float a0 = 0.f, a1 = 0.f, a2 = 0.f, a3 = 0.f;
        for (int e = 0; e < H; e += 8) {
            float m0 = W[(e + 0) * H + h];
            float m1 = W[(e + 1) * H + h];
            float m2 = W[(e + 2) * H + h];
            float m3 = W[(e + 3) * H + h];
            float m4 = W[(e + 4) * H + h];
            float m5 = W[(e + 5) * H + h];
            float m6 = W[(e + 6) * H + h];
            float m7 = W[(e + 7) * H + h];
#pragma unroll
            for (int r = 0; r < 4; ++r) {
                float4 pa = *(const float4*)&p_s[r * E + g * H + e];
                float4 pb = *(const float4*)&p_s[r * E + g * H + e + 4];
                float v = pa.x * m0 + pa.y * m1 + pa.z * m2 + pa.w * m3
                        + pb.x * m4 + pb.y * m5 + pb.z * m6 + pb.w * m7;
                if (r == 0) a0 += v; else if (r == 1) a1 += v;
                else if (r == 2) a2 += v; else a3 += v;
            }
        }
        sp[g][0][h] = a0;
        sp[g][1][h] = a1;
        sp[g][2][h] = a2;
        sp[g][3][h] = a3;
    }
    __syncthreads();
    // combine: thread (g,h) handles rows 2g, 2g+1
    {
        int r0 = g * 2, r1 = r0 + 1;
        sv[r0][h] = sp[0][r0][h] + sp[1][r0][h] + av[h];
        sv[r1][h] = sp[0][r1][h] + sp[1][r1][h] + av[h];
    }
    __syncthreads();

    // W1 stage partials: qp[r][h] = sum_{rr} s[r][rr] * W1[side*H+rr][h]
    // r-half g covers rr in [g*64, g*64+64). sv reads are wave-broadcast.
    {
        const float* W1c = W1 + (side * H + g * 64) * H;
        float a0 = 0.f, a1 = 0.f, a2 = 0.f, a3 = 0.f;
        for (int r = 0; r < 64; r += 8) {
            float w0 = W1c[(r + 0) * H + h];
            float w1 = W1c[(r + 1) * H + h];
            float w2 = W1c[(r + 2) * H + h];
            float w3 = W1c[(r + 3) * H + h];
            float w4 = W1c[(r + 4) * H + h];
            float w5 = W1c[(r + 5) * H + h];
            float w6 = W1c[(r + 6) * H + h];
            float w7 = W1c[(r + 7) * H + h];
#pragma unroll
            for (int rr = 0; rr < 4; ++rr) {
                const float* S = &sv[rr][g * 64 + r];
                float v = S[0] * w0 + S[1] * w1 + S[2] * w2 + S[3] * w3
                        + S[4] * w4 + S[5] * w5 + S[6] * w6 + S[7] * w7;
                if (rr == 0) a0 += v; else if (rr == 1) a1 += v;
                else if (rr == 2) a2 += v; else a3 += v;
            }
        }
        qpp[g][0][h] = a0;
        qpp[g][1][h] = a1;
        qpp[g][2][h] = a2;
        qpp[g][3][h] = a3;
    }
    __syncthreads();
    // combine & write: thread (g,h) writes rows 2g, 2g+1 (f16)
    {
        float bb = side ? 0.f : b1[h];
        int r0 = g * 2, r1 = r0 + 1;
        float v0 = qpp[0][r0][h] + qpp[1][r0][h] + bb;
        float v1 = qpp[0][r1][h] + qpp[1][r1][h] + bb;
        half_t* O = side ? kh : qh;
        O[(i0 + r0) * H + h] = (half_t)v0;
        O[(i0 + r1) * H + h] = (half_t)v1;
    }
}

// pair: exact triangular tiling. 528 blocks, one 32x32 (bi<=bj) tile each.
// Per thread: 4 (i,j) pairs; f16 LDS + fdot2. (Unchanged, harness-verified.)
#define QSTR 136  // halves; 272 B row stride -> conflict-free b128
__global__ __launch_bounds__(256) void pair_kernel(
    const half_t* __restrict__ qh, const half_t* __restrict__ kh,
    const float* __restrict__ W2, const float* __restrict__ b2,
    float* __restrict__ out) {
    int tid = blockIdx.x;
    int bi = (int)((65.0f - sqrtf(4225.0f - 8.0f * (float)tid)) * 0.5f);
    while (bi > 0 && tid < 32 * bi - bi * (bi - 1) / 2) --bi;
    while (tid >= 32 * (bi + 1) - (bi + 1) * bi / 2) ++bi;
    int bj = bi + (tid - (32 * bi - bi * (bi - 1) / 2));

    __shared__ __align__(16) half_t qs[32][QSTR];
    __shared__ __align__(16) half_t ks[32][QSTR];
    __shared__ __align__(16) half_t w2s[H];

    int t = threadIdx.x;
    if (t < H) w2s[t] = (half_t)W2[t];

    const float4* qh4 = (const float4*)(qh + bi * 32 * H);
    const float4* kh4 = (const float4*)(kh + bj * 32 * H);
#pragma unroll
    for (int v = 0; v < 2; ++v) {
        int idx = v * 256 + t;  // 0..511 : 32 rows x 16 float4
        int r = idx >> 4, c = idx & 15;
        float4 q = qh4[idx];
        float4 k = kh4[idx];
        *(float4*)&qs[r][c * 8] = q;
        *(float4*)&ks[r][c * 8] = k;
    }
    __syncthreads();

    int jj  = t & 31;  // k row within tile
    int ti0 = t >> 5;  // q rows ti0, ti0+8, ti0+16, ti0+24
    float b2v = b2[0];
    float acc[4];
#pragma unroll
    for (int u = 0; u < 4; ++u) acc[u] = b2v;

    for (int h8 = 0; h8 < 16; ++h8) {
        float4 wf = *(const float4*)&w2s[h8 * 8];
        float4 kv = *(const float4*)&ks[jj][h8 * 8];
        const hv2* wp = (const hv2*)&wf;
        const hv2* kp2 = (const hv2*)&kv;
#pragma unroll
        for (int u = 0; u < 4; ++u) {
            float4 qf = *(const float4*)&qs[ti0 + u * 8][h8 * 8];
            const hv2* qp2 = (const hv2*)&qf;
#pragma unroll
            for (int s = 0; s < 4; ++s) {
                hv2 sa = relu_add2(qp2[s], kp2[s]);
                acc[u] = dot2_acc(sa, wp[s], acc[u]);
            }
        }
    }

#pragma unroll
    for (int u = 0; u < 4; ++u) {
        int i = bi * 32 + ti0 + u * 8;
        int j = bj * 32 + jj;
        if (j > i) {
            int base = i * (2 * N - i - 1) / 2;
            out[base + (j - i - 1)] = acc[u];
        }
    }
}

extern "C" void kernel_launch(void* const* d_in, const int* in_sizes, int n_in,
                              void* d_out, int out_size, void* d_ws, size_t ws_size,
                              hipStream_t stream) {
    const float* x  = (const float*)d_in[0];
    const float* P  = (const float*)d_in[1];
    const float* Wq = (const float*)d_in[2];
    const float* bq = (const float*)d_in[3];
    const float* Wk = (const float*)d_in[4];
    const float* bk = (const float*)d_in[5];
    const float* Wc = (const float*)d_in[6];
    const float* bc = (const float*)d_in[7];
    const float* W1 = (const float*)d_in[8];
    const float* b1 = (const float*)d_in[9];
    const float* W2 = (const float*)d_in[10];
    const float* b2 = (const float*)d_in[11];
    float* out = (float*)d_out;

    half_t* qh = (half_t*)d_ws;        // 1024*128 halves
    half_t* kh = qh + N * H;           // 1024*128 halves

    proj_kernel<<<512, 256, 0, stream>>>(x, P, Wq, bq, Wk, bk, Wc, bc, W1, b1,
                                         qh, kh);
    pair_kernel<<<528, 256, 0, stream>>>(qh, kh, W2, b2, out);
}

// Round 11
// 91.604 us; speedup vs baseline: 1.6480x; 1.0518x over previous
//
#include <hip/hip_runtime.h>

#define N 1024
#define E 256
#define H 128

typedef _Float16 hv2 __attribute__((ext_vector_type(2)));
typedef _Float16 half_t;

__device__ __forceinline__ float dot2_acc(hv2 a, hv2 b, float c) {
#if __has_builtin(__builtin_amdgcn_fdot2)
    return __builtin_amdgcn_fdot2(a, b, c, false);
#else
    return c + (float)a.x * (float)b.x + (float)a.y * (float)b.y;
#endif
}

__device__ __forceinline__ hv2 relu_add2(hv2 a, hv2 b) {
    hv2 s = a + b;
    hv2 z = (hv2)(_Float16)0.f;
    return __builtin_elementwise_max(s, z);
}

// proj v4: 8-row amortization. 256 blocks x 512 threads (8 waves/CU = 2/SIMD,
// same wave occupancy as R10). Block b: side = b&1, rows i0=(b>>1)*8 .. +7.
// Thread t: h = t&127, g = t>>7 = e-quarter (s-stage) / rr-quarter (W1 stage).
// Each thread accumulates 8 rows in registers per weight column -> per-block
// weight traffic 320 KB serves 8 rows (R10: 4) -> total 82 MB (R10: 164 MB),
// per-thread loads 160 (R10: 320), dependent batches 20 (R10: 40).
// Unlike R9's failed twin (same launch config, NO traffic saving, pure L1-dedup
// bet), the reuse here is structural: each weight element read once per block.
__global__ __launch_bounds__(512) void proj_kernel(
    const float* __restrict__ x, const float* __restrict__ P,
    const float* __restrict__ Wq, const float* __restrict__ bq,
    const float* __restrict__ Wk, const float* __restrict__ bk,
    const float* __restrict__ Wc, const float* __restrict__ bc,
    const float* __restrict__ W1, const float* __restrict__ b1,
    half_t* __restrict__ qh, half_t* __restrict__ kh) {
    __shared__ __align__(16) float xs[E];       // next-state embedding
    __shared__ __align__(16) float p_s[8 * E];  // 8 P rows (8 KB)
    __shared__ float pc[4][H];                  // ctx partials by e-quarter
    __shared__ float av[H];                     // b_side + ctx
    __shared__ float sp[4][8][H];               // s partials (16 KB)
    __shared__ float sv[8][H];                  // s combined (4 KB)
    __shared__ float qpp[4][8][H];              // W1 partials (16 KB)

    int b = blockIdx.x, t = threadIdx.x;
    int side = b & 1;               // 0 = q, 1 = k
    int i0 = (b >> 1) * 8;          // first of 8 rows
    int h = t & (H - 1);
    int g = t >> 7;                 // quarter group 0..3

    if (t < 64) ((float4*)xs)[t] = ((const float4*)x)[t];
    ((float4*)p_s)[t] = ((const float4*)(P + i0 * E))[t];  // 512 f4 = 8 rows
    __syncthreads();

    // ctx partial: quarter g covers e in [g*64, g*64+64)
    {
        const float* Wce = Wc + g * 64 * H;
        const float* xg = xs + g * 64;
        float p = 0.f;
#pragma unroll 8
        for (int e = 0; e < 64; ++e) p += xg[e] * Wce[e * H + h];
        pc[g][h] = p;
    }
    __syncthreads();
    if (t < H) {
        float ctxv = fmaxf(pc[0][t] + pc[1][t] + pc[2][t] + pc[3][t] + bc[t], 0.f);
        av[t] = (side ? bk[t] : bq[t]) + ctxv;
    }
    __syncthreads();

    // s partials: 8 rows, e-quarter g covers e in [g*64, g*64+64) of E
    {
        const float* W = (side ? Wk : Wq) + g * 64 * H;
        float acc[8];
#pragma unroll
        for (int r = 0; r < 8; ++r) acc[r] = 0.f;
        for (int e = 0; e < 64; e += 8) {
            float m0 = W[(e + 0) * H + h];
            float m1 = W[(e + 1) * H + h];
            float m2 = W[(e + 2) * H + h];
            float m3 = W[(e + 3) * H + h];
            float m4 = W[(e + 4) * H + h];
            float m5 = W[(e + 5) * H + h];
            float m6 = W[(e + 6) * H + h];
            float m7 = W[(e + 7) * H + h];
#pragma unroll
            for (int r = 0; r < 8; ++r) {
                float4 pa = *(const float4*)&p_s[r * E + g * 64 + e];
                float4 pb = *(const float4*)&p_s[r * E + g * 64 + e + 4];
                acc[r] += pa.x * m0 + pa.y * m1 + pa.z * m2 + pa.w * m3
                        + pb.x * m4 + pb.y * m5 + pb.z * m6 + pb.w * m7;
            }
        }
#pragma unroll
        for (int r = 0; r < 8; ++r) sp[g][r][h] = acc[r];
    }
    __syncthreads();
    // combine: thread (g,h) handles rows 2g, 2g+1
    {
        int r0 = g * 2, r1 = r0 + 1;
        sv[r0][h] = sp[0][r0][h] + sp[1][r0][h] + sp[2][r0][h] + sp[3][r0][h] + av[h];
        sv[r1][h] = sp[0][r1][h] + sp[1][r1][h] + sp[2][r1][h] + sp[3][r1][h] + av[h];
    }
    __syncthreads();

    // W1 partials: rr-quarter g covers rr in [g*32, g*32+32) of the side-half.
    // sv reads are wave-broadcast (same addr across lanes).
    {
        const float* W1c = W1 + (side * H + g * 32) * H;
        float acc[8];
#pragma unroll
        for (int r = 0; r < 8; ++r) acc[r] = 0.f;
        for (int r = 0; r < 32; r += 8) {
            float w0 = W1c[(r + 0) * H + h];
            float w1 = W1c[(r + 1) * H + h];
            float w2 = W1c[(r + 2) * H + h];
            float w3 = W1c[(r + 3) * H + h];
            float w4 = W1c[(r + 4) * H + h];
            float w5 = W1c[(r + 5) * H + h];
            float w6 = W1c[(r + 6) * H + h];
            float w7 = W1c[(r + 7) * H + h];
#pragma unroll
            for (int rr = 0; rr < 8; ++rr) {
                const float* S = &sv[rr][g * 32 + r];
                acc[rr] += S[0] * w0 + S[1] * w1 + S[2] * w2 + S[3] * w3
                         + S[4] * w4 + S[5] * w5 + S[6] * w6 + S[7] * w7;
            }
        }
#pragma unroll
        for (int rr = 0; rr < 8; ++rr) qpp[g][rr][h] = acc[rr];
    }
    __syncthreads();
    // combine & write: thread (g,h) writes rows 2g, 2g+1 (f16)
    {
        float bb = side ? 0.f : b1[h];
        int r0 = g * 2, r1 = r0 + 1;
        float v0 = qpp[0][r0][h] + qpp[1][r0][h] + qpp[2][r0][h] + qpp[3][r0][h] + bb;
        float v1 = qpp[0][r1][h] + qpp[1][r1][h] + qpp[2][r1][h] + qpp[3][r1][h] + bb;
        half_t* O = side ? kh : qh;
        O[(i0 + r0) * H + h] = (half_t)v0;
        O[(i0 + r1) * H + h] = (half_t)v1;
    }
}

// pair: exact triangular tiling. 528 blocks, one 32x32 (bi<=bj) tile each.
// Per thread: 4 (i,j) pairs; f16 LDS + fdot2. (Unchanged, harness-verified.)
#define QSTR 136  // halves; 272 B row stride -> conflict-free b128
__global__ __launch_bounds__(256) void pair_kernel(
    const half_t* __restrict__ qh, const half_t* __restrict__ kh,
    const float* __restrict__ W2, const float* __restrict__ b2,
    float* __restrict__ out) {
    int tid = blockIdx.x;
    int bi = (int)((65.0f - sqrtf(4225.0f - 8.0f * (float)tid)) * 0.5f);
    while (bi > 0 && tid < 32 * bi - bi * (bi - 1) / 2) --bi;
    while (tid >= 32 * (bi + 1) - (bi + 1) * bi / 2) ++bi;
    int bj = bi + (tid - (32 * bi - bi * (bi - 1) / 2));

    __shared__ __align__(16) half_t qs[32][QSTR];
    __shared__ __align__(16) half_t ks[32][QSTR];
    __shared__ __align__(16) half_t w2s[H];

    int t = threadIdx.x;
    if (t < H) w2s[t] = (half_t)W2[t];

    const float4* qh4 = (const float4*)(qh + bi * 32 * H);
    const float4* kh4 = (const float4*)(kh + bj * 32 * H);
#pragma unroll
    for (int v = 0; v < 2; ++v) {
        int idx = v * 256 + t;  // 0..511 : 32 rows x 16 float4
        int r = idx >> 4, c = idx & 15;
        float4 q = qh4[idx];
        float4 k = kh4[idx];
        *(float4*)&qs[r][c * 8] = q;
        *(float4*)&ks[r][c * 8] = k;
    }
    __syncthreads();

    int jj  = t & 31;  // k row within tile
    int ti0 = t >> 5;  // q rows ti0, ti0+8, ti0+16, ti0+24
    float b2v = b2[0];
    float acc[4];
#pragma unroll
    for (int u = 0; u < 4; ++u) acc[u] = b2v;

    for (int h8 = 0; h8 < 16; ++h8) {
        float4 wf = *(const float4*)&w2s[h8 * 8];
        float4 kv = *(const float4*)&ks[jj][h8 * 8];
        const hv2* wp = (const hv2*)&wf;
        const hv2* kp2 = (const hv2*)&kv;
#pragma unroll
        for (int u = 0; u < 4; ++u) {
            float4 qf = *(const float4*)&qs[ti0 + u * 8][h8 * 8];
            const hv2* qp2 = (const hv2*)&qf;
#pragma unroll
            for (int s = 0; s < 4; ++s) {
                hv2 sa = relu_add2(qp2[s], kp2[s]);
                acc[u] = dot2_acc(sa, wp[s], acc[u]);
            }
        }
    }

#pragma unroll
    for (int u = 0; u < 4; ++u) {
        int i = bi * 32 + ti0 + u * 8;
        int j = bj * 32 + jj;
        if (j > i) {
            int base = i * (2 * N - i - 1) / 2;
            out[base + (j - i - 1)] = acc[u];
        }
    }
}

extern "C" void kernel_launch(void* const* d_in, const int* in_sizes, int n_in,
                              void* d_out, int out_size, void* d_ws, size_t ws_size,
                              hipStream_t stream) {
    const float* x  = (const float*)d_in[0];
    const float* P  = (const float*)d_in[1];
    const float* Wq = (const float*)d_in[2];
    const float* bq = (const float*)d_in[3];
    const float* Wk = (const float*)d_in[4];
    const float* bk = (const float*)d_in[5];
    const float* Wc = (const float*)d_in[6];
    const float* bc = (const float*)d_in[7];
    const float* W1 = (const float*)d_in[8];
    const float* b1 = (const float*)d_in[9];
    const float* W2 = (const float*)d_in[10];
    const float* b2 = (const float*)d_in[11];
    float* out = (float*)d_out;

    half_t* qh = (half_t*)d_ws;        // 1024*128 halves
    half_t* kh = qh + N * H;           // 1024*128 halves

    proj_kernel<<<256, 512, 0, stream>>>(x, P, Wq, bq, Wk, bk, Wc, bc, W1, b1,
                                         qh, kh);
    pair_kernel<<<528, 256, 0, stream>>>(qh, kh, W2, b2, out);
}